// Round 12
// baseline (200.040 us; speedup 1.0000x reference)
//
#include <hip/hip_runtime.h>
#include <stdint.h>
#include <stddef.h>

// ---------------------------------------------------------------------------
// HHGNN. R12 vs R10 (167.2us best; R11 fused-adjbf regressed to 192):
// ONE lever — adj fp32 read EXACTLY once, by a standalone convert kernel.
//  k_conv: adjbf = bf16(adj), contiguous nt-read/stream-write (R11's failure
//    was 8B-scattered in-loop writes; standalone conv writes 1KB/wave lines).
//  k2': A-panel reads adjbf (bf16, L3-resident: 134MB < 256MB, just written)
//    -> half the A bytes, L3-hit latency, no DRAM page thrash on the
//    64B/row strided reads; ds-scatter repack via v_perm_b32 (no cvtpk).
//  k3': = R11's k3 (single gload_lds A staging; passed correctness in R11).
// k0/k1 unchanged from R10. Order: conv, k0, k1, k2, k3 (adjbf stays in L3).
// ws: xT 8.39 + latT 4.19 + WT 0.43 + adjbf 134.2 = 147.2MB.
// ---------------------------------------------------------------------------

typedef float    f32x4_t  __attribute__((ext_vector_type(4)));
typedef __bf16   bf16x8_t __attribute__((ext_vector_type(8)));
typedef unsigned int u32x4_t __attribute__((ext_vector_type(4)));
typedef unsigned int u32x2_t __attribute__((ext_vector_type(2)));

__device__ __forceinline__ unsigned short f2bf(float f) {
    union { float f; unsigned int u; } v; v.f = f;
    unsigned int u = v.u;
    return (unsigned short)((u + 0x7FFFu + ((u >> 16) & 1u)) >> 16);
}

// packed RNE fp32x2 -> bf16x2 (lo=a, hi=b)
__device__ __forceinline__ unsigned int cvtpk(float a, float b) {
    unsigned int r;
    asm("v_cvt_pk_bf16_f32 %0, %1, %2" : "=v"(r) : "v"(a), "v"(b));
    return r;
}

__device__ __forceinline__ bool mask_on(const unsigned char* m, int gid) {
    return (m[gid] | m[(gid >> 2) << 2]) != 0;
}

// byte offset of 16B-granule g in row `row` of a [rows][64] bf16 LDS panel
__device__ __forceinline__ int foff(int row, int g) {
    return row * 128 + (((g) ^ (row & 7)) << 4);
}

// B-panel staging: 128 rows x 64 bf16, one 16B gload_lds per thread x4.
template<int GSTRIDE>
__device__ __forceinline__ void stage_B(const unsigned short* __restrict__ gb,
                                        int k0, unsigned short* ldsB, int t)
{
    const int l = t & 63, w = t >> 6;
    const int hsub = l >> 3;
    const int csrc = ((l & 7) ^ hsub) << 3;
    #pragma unroll
    for (int i = 0; i < 4; ++i) {
        const int hbase = i * 32 + w * 8;
        const unsigned short* src = gb + (size_t)(hbase + hsub) * GSTRIDE + k0 + csrc;
        unsigned short* dst = ldsB + hbase * 64;
        __builtin_amdgcn_global_load_lds(
            (__attribute__((address_space(1))) void*)src,
            (__attribute__((address_space(3))) void*)dst, 16, 0, 0);
    }
}

// A-panel staging (32 rows x 64 bf16), ONE 16B gload_lds per thread.
__device__ __forceinline__ void stage_A3(const unsigned short* __restrict__ ab,
                                         int k0, unsigned short* ldsA, int t)
{
    const int l = t & 63, w = t >> 6;
    const int rsub = l >> 3;
    const int csrc = ((l & 7) ^ rsub) << 3;
    const unsigned short* src = ab + (size_t)(w * 8 + rsub) * 2048 + k0 + csrc;
    unsigned short* dst = ldsA + (w * 8) * 64;
    __builtin_amdgcn_global_load_lds(
        (__attribute__((address_space(1))) void*)src,
        (__attribute__((address_space(3))) void*)dst, 16, 0, 0);
}

// ---------------------------------------------------------------------------
// k_conv: adjbf = bf16(adj) — contiguous stream, 2048 blocks.
// ---------------------------------------------------------------------------
__global__ __launch_bounds__(256) void k_conv(
    const float* __restrict__ adj, unsigned short* __restrict__ adjbf)
{
    const size_t total = (size_t)8 * 4096 * 2048;
    const size_t stride = (size_t)gridDim.x * 256 * 8;
    for (size_t i = ((size_t)blockIdx.x * 256 + threadIdx.x) * 8; i < total; i += stride) {
        f32x4_t a = __builtin_nontemporal_load((const f32x4_t*)(adj + i));
        f32x4_t b = __builtin_nontemporal_load((const f32x4_t*)(adj + i + 4));
        u32x4_t o;
        o[0] = cvtpk(a[0], a[1]); o[1] = cvtpk(a[2], a[3]);
        o[2] = cvtpk(b[0], b[1]); o[3] = cvtpk(b[2], b[3]);
        *(u32x4_t*)(adjbf + i) = o;
    }
}

// ---------------------------------------------------------------------------
// k0: WT[t][d][h] = bf16(W[t][h][d])
// ---------------------------------------------------------------------------
__global__ __launch_bounds__(256) void k0_wtrans(
    const float* __restrict__ W, unsigned short* __restrict__ WT)
{
    __shared__ float tile[128][132];
    const int t = threadIdx.x, ty = blockIdx.x;
    const float* Wt = W + (size_t)ty * 128 * 128;
    for (int it = 0; it < 16; ++it) {
        int idx = it * 256 + t;
        int h = idx >> 5, c = (idx & 31) * 4;
        *(float4*)(&tile[h][c]) = *(const float4*)(Wt + h * 128 + c);
    }
    __syncthreads();
    const int d = t >> 1, half = t & 1, h0 = half * 64;
    unsigned short* out = WT + ((size_t)ty * 128 + d) * 128 + h0;
    #pragma unroll
    for (int ch = 0; ch < 8; ++ch) {
        int h = h0 + ch * 8;
        u32x4_t o;
        o[0] = cvtpk(tile[h + 0][d], tile[h + 1][d]);
        o[1] = cvtpk(tile[h + 2][d], tile[h + 3][d]);
        o[2] = cvtpk(tile[h + 4][d], tile[h + 5][d]);
        o[3] = cvtpk(tile[h + 6][d], tile[h + 7][d]);
        *(u32x4_t*)(out + ch * 8) = o;
    }
}

// ---------------------------------------------------------------------------
// k1: typed linear (MFMA) + bias + mask + LayerNorm -> xT bf16 [B][H][N]
// (unchanged from R10)
// ---------------------------------------------------------------------------
__global__ __launch_bounds__(256) void k1_typed_ln(
    const float* __restrict__ embeds,
    const int*   __restrict__ ntype,
    const unsigned char* __restrict__ mask8,
    const unsigned short* __restrict__ WT,
    const float* __restrict__ bias,
    const float* __restrict__ gamma,
    const float* __restrict__ beta,
    unsigned short* __restrict__ xT)
{
    __shared__ unsigned short e_lds[64][136];
    __shared__ unsigned short y_lds[64][136];
    __shared__ unsigned short lists[13][64];
    __shared__ int cnt[13];
    __shared__ int grp_ty[32], grp_base[32], grp_n;
    __shared__ unsigned char msk[64];
    __shared__ float g_lds[128], be_lds[128];

    const int t   = threadIdx.x;
    const int bid = blockIdx.x;
    const int b   = bid & 7;
    const int n0  = (bid >> 3) << 6;
    const int gbase = b * 4096 + n0;
    const float* ebase = embeds + (size_t)gbase * 128;

    {
        const int n = t >> 2, q = t & 3;
        const float* src = ebase + n * 128 + q * 32;
        #pragma unroll
        for (int c = 0; c < 4; ++c) {
            f32x4_t va = *(const f32x4_t*)(src + c * 8);
            f32x4_t vb = *(const f32x4_t*)(src + c * 8 + 4);
            u32x4_t o;
            o[0] = cvtpk(va[0], va[1]); o[1] = cvtpk(va[2], va[3]);
            o[2] = cvtpk(vb[0], vb[1]); o[3] = cvtpk(vb[2], vb[3]);
            *(u32x4_t*)(&e_lds[n][q * 32 + c * 8]) = o;
        }
    }
    if (t < 128) { g_lds[t] = gamma[t]; be_lds[t] = beta[t]; }
    if (t < 64)  msk[t] = mask_on(mask8, gbase + t) ? 1 : 0;
    if (t < 13)  cnt[t] = 0;
    __syncthreads();

    if (t < 64) {
        int ty = ntype[(size_t)gbase + t];
        int slot = atomicAdd(&cnt[ty], 1);
        lists[ty][slot] = (unsigned short)t;
    }
    __syncthreads();
    if (t == 0) {
        int g = 0;
        for (int ty = 0; ty < 13; ++ty) {
            int c = cnt[ty];
            for (int base = 0; base < c; base += 16) {
                grp_ty[g] = ty; grp_base[g] = base; ++g;
            }
        }
        grp_n = g;
    }
    __syncthreads();

    const int NG   = grp_n;
    const int lane = t & 63, wv = t >> 6;
    const int fr = lane & 15, fg = lane >> 4;
    const int d0 = wv * 32;

    for (int g = 0; g < NG; ++g) {
        const int ty = grp_ty[g], base = grp_base[g];
        const int cend = cnt[ty] - 1;
        const int nodeA = lists[ty][min(base + fr, cend)];

        bf16x8_t afr[4];
        #pragma unroll
        for (int kk = 0; kk < 4; ++kk)
            afr[kk] = __builtin_bit_cast(bf16x8_t,
                *(const u32x4_t*)(&e_lds[nodeA][kk * 32 + fg * 8]));

        const unsigned short* wt = WT + (size_t)ty * 128 * 128;
        f32x4_t acc0 = f32x4_t{0.f, 0.f, 0.f, 0.f};
        f32x4_t acc1 = f32x4_t{0.f, 0.f, 0.f, 0.f};
        #pragma unroll
        for (int kk = 0; kk < 4; ++kk) {
            bf16x8_t b0 = __builtin_bit_cast(bf16x8_t,
                *(const u32x4_t*)(wt + (size_t)(d0 + fr) * 128 + kk * 32 + fg * 8));
            bf16x8_t b1 = __builtin_bit_cast(bf16x8_t,
                *(const u32x4_t*)(wt + (size_t)(d0 + 16 + fr) * 128 + kk * 32 + fg * 8));
            acc0 = __builtin_amdgcn_mfma_f32_16x16x32_bf16(afr[kk], b0, acc0, 0, 0, 0);
            acc1 = __builtin_amdgcn_mfma_f32_16x16x32_bf16(afr[kk], b1, acc1, 0, 0, 0);
        }

        const float bs0 = bias[ty * 128 + d0 + fr];
        const float bs1 = bias[ty * 128 + d0 + 16 + fr];
        #pragma unroll
        for (int j = 0; j < 4; ++j) {
            const int nd = lists[ty][min(base + fg * 4 + j, cend)];
            if (msk[nd]) {
                y_lds[nd][d0 + fr]      = f2bf(acc0[j] + bs0);
                y_lds[nd][d0 + 16 + fr] = f2bf(acc1[j] + bs1);
            } else {
                y_lds[nd][d0 + fr]      = e_lds[nd][d0 + fr];
                y_lds[nd][d0 + 16 + fr] = e_lds[nd][d0 + 16 + fr];
            }
        }
    }
    __syncthreads();

    for (int i = 0; i < 16; ++i) {
        const int n = wv + i * 4;
        unsigned int u = *(const unsigned int*)(&y_lds[n][lane * 2]);
        float vx = __builtin_bit_cast(float, u << 16);
        float vy = __builtin_bit_cast(float, u & 0xffff0000u);
        float s = vx + vy;
        float q = vx * vx + vy * vy;
        #pragma unroll
        for (int mw = 32; mw >= 1; mw >>= 1) {
            s += __shfl_xor(s, mw);
            q += __shfl_xor(q, mw);
        }
        const float mu  = s * 0.0078125f;
        const float var = q * 0.0078125f - mu * mu;
        const float r   = rsqrtf(var + 1e-5f);
        const float ox = (vx - mu) * r * g_lds[lane * 2]     + be_lds[lane * 2];
        const float oy = (vy - mu) * r * g_lds[lane * 2 + 1] + be_lds[lane * 2 + 1];
        *(unsigned int*)(&y_lds[n][lane * 2]) = cvtpk(ox, oy);
    }
    __syncthreads();

    const int nl = t & 63, hg = t >> 6;
    unsigned short* xrow = xT + (size_t)b * 128 * 4096 + n0 + nl;
    for (int i = 0; i < 32; ++i) {
        const int h = hg * 32 + i;
        xrow[(size_t)h * 4096] = y_lds[nl][h];
    }
}

// ---------------------------------------------------------------------------
// Kernel 2: latT[b][h][m] = sum_n adjbf[b][n][m] * x[b][n][h]
// A from bf16 adjbf (L3-resident): 2x8B loads/thread, v_perm repack,
// same swizzled ds-scatter + schedule as R10.
// ---------------------------------------------------------------------------
__global__ __launch_bounds__(256) void k2_lat(
    const unsigned short* __restrict__ adjbf,
    const unsigned short* __restrict__ xT,
    unsigned short* __restrict__ latT)
{
    __shared__ unsigned short Al[2][32 * 64];
    __shared__ unsigned short Bl[2][128 * 64];

    const int t   = threadIdx.x;
    const int bid = blockIdx.x;
    const int b   = bid & 7;
    const int m0  = (bid >> 3) << 5;
    const unsigned short* ab = adjbf + (size_t)b * 4096 * 2048;
    const unsigned short* xb = xT + (size_t)b * 128 * 4096;

    const int lane = t & 63, wv = t >> 6;
    const int wm = wv & 1, wh = wv >> 1;

    const int a_kp = t >> 3;        // k-pair 0..31 (n = 2*a_kp, 2*a_kp+1)
    const int a_m  = (t & 7) << 2;  // m chunk base

    const int fr = lane & 15, fg = lane >> 4;
    int offA[2], offB[4][2];
    #pragma unroll
    for (int kk = 0; kk < 2; ++kk) offA[kk] = foff(wm * 16 + fr, kk * 4 + fg);
    #pragma unroll
    for (int j = 0; j < 4; ++j)
        #pragma unroll
        for (int kk = 0; kk < 2; ++kk)
            offB[j][kk] = foff(wh * 64 + j * 16 + fr, kk * 4 + fg);

    u32x2_t ar0, ar1;               // 4 bf16 each: rows n=2kp, 2kp+1
    auto LOAD_A = [&](int k0) {
        const unsigned short* p = ab + (size_t)(k0 + a_kp * 2) * 2048 + m0 + a_m;
        ar0 = *(const u32x2_t*)(p);
        ar1 = *(const u32x2_t*)(p + 2048);
    };
    auto WRITE_A = [&](int buf) {
        const int g = a_kp >> 2, wrd = a_kp & 3;
        // pk[j] = bf(n0,m=a_m+j) | bf(n1,m=a_m+j)<<16  via v_perm_b32
        unsigned int pk[4];
        pk[0] = __builtin_amdgcn_perm(ar1[0], ar0[0], 0x05040100u);
        pk[1] = __builtin_amdgcn_perm(ar1[0], ar0[0], 0x07060302u);
        pk[2] = __builtin_amdgcn_perm(ar1[1], ar0[1], 0x05040100u);
        pk[3] = __builtin_amdgcn_perm(ar1[1], ar0[1], 0x07060302u);
        #pragma unroll
        for (int j = 0; j < 4; ++j) {
            const int m = a_m + j;
            *(unsigned int*)((char*)(&Al[buf][0]) + m * 128 + ((g ^ (m & 7)) << 4) + wrd * 4) = pk[j];
        }
    };

    f32x4_t acc[4];
    #pragma unroll
    for (int j = 0; j < 4; ++j) acc[j] = f32x4_t{0.f, 0.f, 0.f, 0.f};

    LOAD_A(0);
    stage_B<4096>(xb, 0, &Bl[0][0], t);
    WRITE_A(0);
    __syncthreads();

    for (int s = 0; s < 64; ++s) {
        const int buf = s & 1;
        if (s < 63) {
            LOAD_A((s + 1) * 64);
            stage_B<4096>(xb, (s + 1) * 64, &Bl[buf ^ 1][0], t);
        }
        bf16x8_t af[2];
        #pragma unroll
        for (int kk = 0; kk < 2; ++kk)
            af[kk] = __builtin_bit_cast(bf16x8_t,
                *(const u32x4_t*)((const char*)(&Al[buf][0]) + offA[kk]));
        #pragma unroll
        for (int j = 0; j < 4; ++j) {
            #pragma unroll
            for (int kk = 0; kk < 2; ++kk) {
                bf16x8_t bfj = __builtin_bit_cast(bf16x8_t,
                    *(const u32x4_t*)((const char*)(&Bl[buf][0]) + offB[j][kk]));
                acc[j] = __builtin_amdgcn_mfma_f32_16x16x32_bf16(af[kk], bfj, acc[j], 0, 0, 0);
            }
        }
        if (s < 63) WRITE_A(buf ^ 1);
        __syncthreads();
    }

    const int mrow = m0 + wm * 16 + (lane >> 4) * 4;
    #pragma unroll
    for (int j = 0; j < 4; ++j) {
        int col = wh * 64 + j * 16 + fr;
        unsigned int o0 = cvtpk(acc[j][0], acc[j][1]);
        unsigned int o1 = cvtpk(acc[j][2], acc[j][3]);
        unsigned int* dst = (unsigned int*)(latT + (size_t)(b * 128 + col) * 2048 + mrow);
        dst[0] = o0; dst[1] = o1;
    }
}

// ---------------------------------------------------------------------------
// Kernel 3: ret[b][n][h] = sum_m adjbf[b][n][m] * latT[b][h][m]
// (R11's k3 verbatim — gload_lds A staging; correctness proven in R11)
// ---------------------------------------------------------------------------
__global__ __launch_bounds__(256) void k3_ret(
    const unsigned short* __restrict__ adjbf,
    const unsigned short* __restrict__ latT,
    float* __restrict__ ret)
{
    __shared__ unsigned short Al[2][32 * 64];
    __shared__ unsigned short Bl[2][128 * 64];

    const int t   = threadIdx.x;
    const int bid = blockIdx.x;
    const int b   = bid & 7;
    const int n0  = (bid >> 3) << 5;
    const unsigned short* ab = adjbf + (size_t)b * 4096 * 2048 + (size_t)n0 * 2048;
    const unsigned short* lb = latT + (size_t)b * 128 * 2048;

    const int lane = t & 63, wv = t >> 6;
    const int wn = wv & 1, wh = wv >> 1;

    const int fr = lane & 15, fg = lane >> 4;
    int offA[2], offB[4][2];
    #pragma unroll
    for (int kk = 0; kk < 2; ++kk) offA[kk] = foff(wn * 16 + fr, kk * 4 + fg);
    #pragma unroll
    for (int j = 0; j < 4; ++j)
        #pragma unroll
        for (int kk = 0; kk < 2; ++kk)
            offB[j][kk] = foff(wh * 64 + j * 16 + fr, kk * 4 + fg);

    f32x4_t acc[4];
    #pragma unroll
    for (int j = 0; j < 4; ++j) acc[j] = f32x4_t{0.f, 0.f, 0.f, 0.f};

    stage_A3(ab, 0, &Al[0][0], t);
    stage_B<2048>(lb, 0, &Bl[0][0], t);
    __syncthreads();

    for (int s = 0; s < 32; ++s) {
        const int buf = s & 1;
        if (s < 31) {
            stage_A3(ab, (s + 1) * 64, &Al[buf ^ 1][0], t);
            stage_B<2048>(lb, (s + 1) * 64, &Bl[buf ^ 1][0], t);
        }
        bf16x8_t af[2];
        #pragma unroll
        for (int kk = 0; kk < 2; ++kk)
            af[kk] = __builtin_bit_cast(bf16x8_t,
                *(const u32x4_t*)((const char*)(&Al[buf][0]) + offA[kk]));
        #pragma unroll
        for (int j = 0; j < 4; ++j) {
            #pragma unroll
            for (int kk = 0; kk < 2; ++kk) {
                bf16x8_t bfj = __builtin_bit_cast(bf16x8_t,
                    *(const u32x4_t*)((const char*)(&Bl[buf][0]) + offB[j][kk]));
                acc[j] = __builtin_amdgcn_mfma_f32_16x16x32_bf16(af[kk], bfj, acc[j], 0, 0, 0);
            }
        }
        __syncthreads();
    }

    const int nrow = n0 + wn * 16 + (lane >> 4) * 4;
    #pragma unroll
    for (int j = 0; j < 4; ++j) {
        int col = wh * 64 + j * 16 + fr;
        #pragma unroll
        for (int jj = 0; jj < 4; ++jj) {
            ret[((size_t)b * 4096 + nrow + jj) * 128 + col] = acc[j][jj];
        }
    }
}

// ---------------------------------------------------------------------------
extern "C" void kernel_launch(void* const* d_in, const int* in_sizes, int n_in,
                              void* d_out, int out_size, void* d_ws, size_t ws_size,
                              hipStream_t stream) {
    const float* adj    = (const float*)d_in[0];
    const float* embeds = (const float*)d_in[1];
    const int*   ntype  = (const int*)d_in[2];
    const unsigned char* mask8 = (const unsigned char*)d_in[3];
    const float* W      = (const float*)d_in[4];
    const float* bias   = (const float*)d_in[5];
    const float* gamma  = (const float*)d_in[6];
    const float* beta   = (const float*)d_in[7];
    float* ret = (float*)d_out;

    unsigned short* xT    = (unsigned short*)d_ws;                  // 8.39 MB
    unsigned short* latT  = xT + (size_t)8 * 128 * 4096;            // 4.19 MB
    unsigned short* WT    = latT + (size_t)8 * 128 * 2048;          // 0.43 MB
    unsigned short* adjbf = WT + (size_t)13 * 128 * 128;            // 134.2 MB
    // ws needed: 147.2 MB

    hipLaunchKernelGGL(k_conv, dim3(2048), dim3(256), 0, stream, adj, adjbf);
    hipLaunchKernelGGL(k0_wtrans, dim3(13), dim3(256), 0, stream, W, WT);
    hipLaunchKernelGGL(k1_typed_ln, dim3(512), dim3(256), 0, stream,
                       embeds, ntype, mask8, WT, bias, gamma, beta, xT);
    hipLaunchKernelGGL(k2_lat, dim3(512), dim3(256), 0, stream, adjbf, xT, latT);
    hipLaunchKernelGGL(k3_ret, dim3(1024), dim3(256), 0, stream, adjbf, latT, ret);
}

// Round 13
// 167.629 us; speedup vs baseline: 1.1933x; 1.1933x over previous
//
#include <hip/hip_runtime.h>
#include <stdint.h>
#include <stddef.h>

// ---------------------------------------------------------------------------
// HHGNN. R13 vs R10 (167.2us best; R11/R12 byte-reduction regressed —
// GEMMs are LATENCY-bound: halving A-bytes saved only ~32us):
// ONE lever — k2 BK 64 -> 128. Same grid (512, 2 blocks/CU either way:
// grid-limited), same total bytes, but 2x compute + 2x in-flight per step
// and half the barriers -> per-step latency exposure amortized 2x.
// LDS k2: Al 2x8KB + Bl 2x32KB = 80KB (2/CU). 16-granule XOR swizzle
// (g ^ row&15) re-derived: frag reads + A ds_writes <=2-way (free).
// k0/k1/k3 byte-identical to R10.
// ws: xT 8.39 + latT 4.19 + WT 0.43 = 13.0MB.
// ---------------------------------------------------------------------------

typedef float    f32x4_t  __attribute__((ext_vector_type(4)));
typedef __bf16   bf16x8_t __attribute__((ext_vector_type(8)));
typedef unsigned int u32x4_t __attribute__((ext_vector_type(4)));
typedef unsigned int u32x2_t __attribute__((ext_vector_type(2)));

__device__ __forceinline__ unsigned short f2bf(float f) {
    union { float f; unsigned int u; } v; v.f = f;
    unsigned int u = v.u;
    return (unsigned short)((u + 0x7FFFu + ((u >> 16) & 1u)) >> 16);
}

// packed RNE fp32x2 -> bf16x2 (lo=a, hi=b)
__device__ __forceinline__ unsigned int cvtpk(float a, float b) {
    unsigned int r;
    asm("v_cvt_pk_bf16_f32 %0, %1, %2" : "=v"(r) : "v"(a), "v"(b));
    return r;
}

__device__ __forceinline__ bool mask_on(const unsigned char* m, int gid) {
    return (m[gid] | m[(gid >> 2) << 2]) != 0;
}

// [rows][64] bf16 panels (8 granules/row), swizzle g ^ (row&7)
__device__ __forceinline__ int foff(int row, int g) {
    return row * 128 + (((g) ^ (row & 7)) << 4);
}
// [rows][128] bf16 panels (16 granules/row), swizzle g ^ (row&15)
__device__ __forceinline__ int foff128(int row, int g) {
    return row * 256 + (((g) ^ (row & 15)) << 4);
}

// B-panel staging, 128 rows x 64 bf16 (BK=64 kernels)
template<int GSTRIDE>
__device__ __forceinline__ void stage_B(const unsigned short* __restrict__ gb,
                                        int k0, unsigned short* ldsB, int t)
{
    const int l = t & 63, w = t >> 6;
    const int hsub = l >> 3;
    const int csrc = ((l & 7) ^ hsub) << 3;
    #pragma unroll
    for (int i = 0; i < 4; ++i) {
        const int hbase = i * 32 + w * 8;
        const unsigned short* src = gb + (size_t)(hbase + hsub) * GSTRIDE + k0 + csrc;
        unsigned short* dst = ldsB + hbase * 64;
        __builtin_amdgcn_global_load_lds(
            (__attribute__((address_space(1))) void*)src,
            (__attribute__((address_space(3))) void*)dst, 16, 0, 0);
    }
}

// B-panel staging, 128 rows x 128 bf16 (BK=128, k2): 8 issues/wave,
// 4 rows per issue; source granule pre-swizzled (l&15) ^ (row&15).
template<int GSTRIDE>
__device__ __forceinline__ void stage_B128(const unsigned short* __restrict__ gb,
                                           int k0, unsigned short* ldsB, int t)
{
    const int l = t & 63, w = t >> 6;
    const int rsub = l >> 4;                      // 0..3 row within group
    #pragma unroll
    for (int i = 0; i < 8; ++i) {
        const int rbase = w * 32 + i * 4;
        const int row = rbase + rsub;
        const int csrc = (((l & 15) ^ (row & 15)) << 3);
        const unsigned short* src = gb + (size_t)row * GSTRIDE + k0 + csrc;
        unsigned short* dst = ldsB + rbase * 128;  // wave-uniform base
        __builtin_amdgcn_global_load_lds(
            (__attribute__((address_space(1))) void*)src,
            (__attribute__((address_space(3))) void*)dst, 16, 0, 0);
    }
}

// ---------------------------------------------------------------------------
// k0: WT[t][d][h] = bf16(W[t][h][d])
// ---------------------------------------------------------------------------
__global__ __launch_bounds__(256) void k0_wtrans(
    const float* __restrict__ W, unsigned short* __restrict__ WT)
{
    __shared__ float tile[128][132];
    const int t = threadIdx.x, ty = blockIdx.x;
    const float* Wt = W + (size_t)ty * 128 * 128;
    for (int it = 0; it < 16; ++it) {
        int idx = it * 256 + t;
        int h = idx >> 5, c = (idx & 31) * 4;
        *(float4*)(&tile[h][c]) = *(const float4*)(Wt + h * 128 + c);
    }
    __syncthreads();
    const int d = t >> 1, half = t & 1, h0 = half * 64;
    unsigned short* out = WT + ((size_t)ty * 128 + d) * 128 + h0;
    #pragma unroll
    for (int ch = 0; ch < 8; ++ch) {
        int h = h0 + ch * 8;
        u32x4_t o;
        o[0] = cvtpk(tile[h + 0][d], tile[h + 1][d]);
        o[1] = cvtpk(tile[h + 2][d], tile[h + 3][d]);
        o[2] = cvtpk(tile[h + 4][d], tile[h + 5][d]);
        o[3] = cvtpk(tile[h + 6][d], tile[h + 7][d]);
        *(u32x4_t*)(out + ch * 8) = o;
    }
}

// ---------------------------------------------------------------------------
// k1: typed linear (MFMA) + bias + mask + LayerNorm -> xT bf16 [B][H][N]
// (unchanged from R10)
// ---------------------------------------------------------------------------
__global__ __launch_bounds__(256) void k1_typed_ln(
    const float* __restrict__ embeds,
    const int*   __restrict__ ntype,
    const unsigned char* __restrict__ mask8,
    const unsigned short* __restrict__ WT,
    const float* __restrict__ bias,
    const float* __restrict__ gamma,
    const float* __restrict__ beta,
    unsigned short* __restrict__ xT)
{
    __shared__ unsigned short e_lds[64][136];
    __shared__ unsigned short y_lds[64][136];
    __shared__ unsigned short lists[13][64];
    __shared__ int cnt[13];
    __shared__ int grp_ty[32], grp_base[32], grp_n;
    __shared__ unsigned char msk[64];
    __shared__ float g_lds[128], be_lds[128];

    const int t   = threadIdx.x;
    const int bid = blockIdx.x;
    const int b   = bid & 7;
    const int n0  = (bid >> 3) << 6;
    const int gbase = b * 4096 + n0;
    const float* ebase = embeds + (size_t)gbase * 128;

    {
        const int n = t >> 2, q = t & 3;
        const float* src = ebase + n * 128 + q * 32;
        #pragma unroll
        for (int c = 0; c < 4; ++c) {
            f32x4_t va = *(const f32x4_t*)(src + c * 8);
            f32x4_t vb = *(const f32x4_t*)(src + c * 8 + 4);
            u32x4_t o;
            o[0] = cvtpk(va[0], va[1]); o[1] = cvtpk(va[2], va[3]);
            o[2] = cvtpk(vb[0], vb[1]); o[3] = cvtpk(vb[2], vb[3]);
            *(u32x4_t*)(&e_lds[n][q * 32 + c * 8]) = o;
        }
    }
    if (t < 128) { g_lds[t] = gamma[t]; be_lds[t] = beta[t]; }
    if (t < 64)  msk[t] = mask_on(mask8, gbase + t) ? 1 : 0;
    if (t < 13)  cnt[t] = 0;
    __syncthreads();

    if (t < 64) {
        int ty = ntype[(size_t)gbase + t];
        int slot = atomicAdd(&cnt[ty], 1);
        lists[ty][slot] = (unsigned short)t;
    }
    __syncthreads();
    if (t == 0) {
        int g = 0;
        for (int ty = 0; ty < 13; ++ty) {
            int c = cnt[ty];
            for (int base = 0; base < c; base += 16) {
                grp_ty[g] = ty; grp_base[g] = base; ++g;
            }
        }
        grp_n = g;
    }
    __syncthreads();

    const int NG   = grp_n;
    const int lane = t & 63, wv = t >> 6;
    const int fr = lane & 15, fg = lane >> 4;
    const int d0 = wv * 32;

    for (int g = 0; g < NG; ++g) {
        const int ty = grp_ty[g], base = grp_base[g];
        const int cend = cnt[ty] - 1;
        const int nodeA = lists[ty][min(base + fr, cend)];

        bf16x8_t afr[4];
        #pragma unroll
        for (int kk = 0; kk < 4; ++kk)
            afr[kk] = __builtin_bit_cast(bf16x8_t,
                *(const u32x4_t*)(&e_lds[nodeA][kk * 32 + fg * 8]));

        const unsigned short* wt = WT + (size_t)ty * 128 * 128;
        f32x4_t acc0 = f32x4_t{0.f, 0.f, 0.f, 0.f};
        f32x4_t acc1 = f32x4_t{0.f, 0.f, 0.f, 0.f};
        #pragma unroll
        for (int kk = 0; kk < 4; ++kk) {
            bf16x8_t b0 = __builtin_bit_cast(bf16x8_t,
                *(const u32x4_t*)(wt + (size_t)(d0 + fr) * 128 + kk * 32 + fg * 8));
            bf16x8_t b1 = __builtin_bit_cast(bf16x8_t,
                *(const u32x4_t*)(wt + (size_t)(d0 + 16 + fr) * 128 + kk * 32 + fg * 8));
            acc0 = __builtin_amdgcn_mfma_f32_16x16x32_bf16(afr[kk], b0, acc0, 0, 0, 0);
            acc1 = __builtin_amdgcn_mfma_f32_16x16x32_bf16(afr[kk], b1, acc1, 0, 0, 0);
        }

        const float bs0 = bias[ty * 128 + d0 + fr];
        const float bs1 = bias[ty * 128 + d0 + 16 + fr];
        #pragma unroll
        for (int j = 0; j < 4; ++j) {
            const int nd = lists[ty][min(base + fg * 4 + j, cend)];
            if (msk[nd]) {
                y_lds[nd][d0 + fr]      = f2bf(acc0[j] + bs0);
                y_lds[nd][d0 + 16 + fr] = f2bf(acc1[j] + bs1);
            } else {
                y_lds[nd][d0 + fr]      = e_lds[nd][d0 + fr];
                y_lds[nd][d0 + 16 + fr] = e_lds[nd][d0 + 16 + fr];
            }
        }
    }
    __syncthreads();

    for (int i = 0; i < 16; ++i) {
        const int n = wv + i * 4;
        unsigned int u = *(const unsigned int*)(&y_lds[n][lane * 2]);
        float vx = __builtin_bit_cast(float, u << 16);
        float vy = __builtin_bit_cast(float, u & 0xffff0000u);
        float s = vx + vy;
        float q = vx * vx + vy * vy;
        #pragma unroll
        for (int mw = 32; mw >= 1; mw >>= 1) {
            s += __shfl_xor(s, mw);
            q += __shfl_xor(q, mw);
        }
        const float mu  = s * 0.0078125f;
        const float var = q * 0.0078125f - mu * mu;
        const float r   = rsqrtf(var + 1e-5f);
        const float ox = (vx - mu) * r * g_lds[lane * 2]     + be_lds[lane * 2];
        const float oy = (vy - mu) * r * g_lds[lane * 2 + 1] + be_lds[lane * 2 + 1];
        *(unsigned int*)(&y_lds[n][lane * 2]) = cvtpk(ox, oy);
    }
    __syncthreads();

    const int nl = t & 63, hg = t >> 6;
    unsigned short* xrow = xT + (size_t)b * 128 * 4096 + n0 + nl;
    for (int i = 0; i < 32; ++i) {
        const int h = hg * 32 + i;
        xrow[(size_t)h * 4096] = y_lds[nl][h];
    }
}

// ---------------------------------------------------------------------------
// Kernel 2: latT[b][h][m] = sum_n adj[b][n][m] * x[b][n][h]
// BK=128, 32 steps. grid 512 (2 blocks/CU, grid-limited). 4 waves (2m x 2h).
// LDS: Al[2][32][128] + Bl[2][128][128] = 80KB.
// ---------------------------------------------------------------------------
__global__ __launch_bounds__(256) void k2_lat(
    const float* __restrict__ adj,
    const unsigned short* __restrict__ xT,
    unsigned short* __restrict__ latT)
{
    __shared__ unsigned short Al[2][32 * 128];
    __shared__ unsigned short Bl[2][128 * 128];

    const int t   = threadIdx.x;
    const int bid = blockIdx.x;
    const int b   = bid & 7;
    const int m0  = (bid >> 3) << 5;
    const float* adjb = adj + (size_t)b * 4096 * 2048;
    const unsigned short* xb = xT + (size_t)b * 128 * 4096;

    const int lane = t & 63, wv = t >> 6;
    const int wm = wv & 1, wh = wv >> 1;

    const int a_kp = t >> 2;        // n-pair 0..63
    const int a_m  = (t & 3) << 3;  // 8 m's

    const int fr = lane & 15, fg = lane >> 4;
    int offA[4], offB[4][4];
    #pragma unroll
    for (int kk = 0; kk < 4; ++kk) offA[kk] = foff128(wm * 16 + fr, kk * 4 + fg);
    #pragma unroll
    for (int j = 0; j < 4; ++j)
        #pragma unroll
        for (int kk = 0; kk < 4; ++kk)
            offB[j][kk] = foff128(wh * 64 + j * 16 + fr, kk * 4 + fg);

    f32x4_t ar0a, ar0b, ar1a, ar1b;
    auto LOAD_A = [&](int k0) {
        const float* p = adjb + (size_t)(k0 + a_kp * 2) * 2048 + m0 + a_m;
        ar0a = *(const f32x4_t*)(p);
        ar0b = *(const f32x4_t*)(p + 4);
        ar1a = *(const f32x4_t*)(p + 2048);
        ar1b = *(const f32x4_t*)(p + 2052);
    };
    auto WRITE_A = [&](int buf) {
        const int g = a_kp >> 2, wrd = a_kp & 3;
        unsigned int pk[8];
        pk[0] = cvtpk(ar0a[0], ar1a[0]); pk[1] = cvtpk(ar0a[1], ar1a[1]);
        pk[2] = cvtpk(ar0a[2], ar1a[2]); pk[3] = cvtpk(ar0a[3], ar1a[3]);
        pk[4] = cvtpk(ar0b[0], ar1b[0]); pk[5] = cvtpk(ar0b[1], ar1b[1]);
        pk[6] = cvtpk(ar0b[2], ar1b[2]); pk[7] = cvtpk(ar0b[3], ar1b[3]);
        #pragma unroll
        for (int j = 0; j < 8; ++j) {
            const int m = a_m + j;
            *(unsigned int*)((char*)(&Al[buf][0]) + m * 256
                + (((g ^ (m & 15)) & 15) << 4) + wrd * 4) = pk[j];
        }
    };

    f32x4_t acc[4];
    #pragma unroll
    for (int j = 0; j < 4; ++j) acc[j] = f32x4_t{0.f, 0.f, 0.f, 0.f};

    LOAD_A(0);
    stage_B128<4096>(xb, 0, &Bl[0][0], t);
    WRITE_A(0);
    __syncthreads();

    for (int s = 0; s < 32; ++s) {
        const int buf = s & 1;
        if (s < 31) {
            LOAD_A((s + 1) * 128);
            stage_B128<4096>(xb, (s + 1) * 128, &Bl[buf ^ 1][0], t);
        }
        bf16x8_t af[4];
        #pragma unroll
        for (int kk = 0; kk < 4; ++kk)
            af[kk] = __builtin_bit_cast(bf16x8_t,
                *(const u32x4_t*)((const char*)(&Al[buf][0]) + offA[kk]));
        #pragma unroll
        for (int j = 0; j < 4; ++j) {
            #pragma unroll
            for (int kk = 0; kk < 4; ++kk) {
                bf16x8_t bfj = __builtin_bit_cast(bf16x8_t,
                    *(const u32x4_t*)((const char*)(&Bl[buf][0]) + offB[j][kk]));
                acc[j] = __builtin_amdgcn_mfma_f32_16x16x32_bf16(af[kk], bfj, acc[j], 0, 0, 0);
            }
        }
        if (s < 31) WRITE_A(buf ^ 1);
        __syncthreads();
    }

    const int mrow = m0 + wm * 16 + (lane >> 4) * 4;
    #pragma unroll
    for (int j = 0; j < 4; ++j) {
        int col = wh * 64 + j * 16 + fr;
        unsigned int o0 = cvtpk(acc[j][0], acc[j][1]);
        unsigned int o1 = cvtpk(acc[j][2], acc[j][3]);
        unsigned int* dst = (unsigned int*)(latT + (size_t)(b * 128 + col) * 2048 + mrow);
        dst[0] = o0; dst[1] = o1;
    }
}

// ---------------------------------------------------------------------------
// Kernel 3 (R10-exact): ret[b][n][h] = sum_m adj[b][n][m] * latT[b][h][m]
// ---------------------------------------------------------------------------
__global__ __launch_bounds__(256) void k3_ret(
    const float* __restrict__ adj,
    const unsigned short* __restrict__ latT,
    float* __restrict__ ret)
{
    __shared__ unsigned short Al[2][32 * 64];
    __shared__ unsigned short Bl[2][128 * 64];

    const int t   = threadIdx.x;
    const int bid = blockIdx.x;
    const int b   = bid & 7;
    const int n0  = (bid >> 3) << 5;
    const float* adjb = adj + (size_t)b * 4096 * 2048;
    const unsigned short* lb = latT + (size_t)b * 128 * 2048;

    const int lane = t & 63, wv = t >> 6;
    const int wn = wv & 1, wh = wv >> 1;

    const int a_r = t >> 3;
    const int a_c = t & 7;

    const int fr = lane & 15, fg = lane >> 4;
    int offA[2], offB[4][2];
    #pragma unroll
    for (int kk = 0; kk < 2; ++kk) offA[kk] = foff(wn * 16 + fr, kk * 4 + fg);
    #pragma unroll
    for (int j = 0; j < 4; ++j)
        #pragma unroll
        for (int kk = 0; kk < 2; ++kk)
            offB[j][kk] = foff(wh * 64 + j * 16 + fr, kk * 4 + fg);

    f32x4_t ar0, ar1;
    auto LOAD_A = [&](int k0) {
        const float* p = adjb + (size_t)(n0 + a_r) * 2048 + k0 + a_c * 8;
        ar0 = *(const f32x4_t*)(p);
        ar1 = *(const f32x4_t*)(p + 4);
    };
    auto WRITE_A = [&](int buf) {
        u32x4_t pk;
        pk[0] = cvtpk(ar0[0], ar0[1]);
        pk[1] = cvtpk(ar0[2], ar0[3]);
        pk[2] = cvtpk(ar1[0], ar1[1]);
        pk[3] = cvtpk(ar1[2], ar1[3]);
        *(u32x4_t*)((char*)(&Al[buf][0]) + a_r * 128 + ((a_c ^ (a_r & 7)) << 4)) = pk;
    };

    f32x4_t acc[4];
    #pragma unroll
    for (int j = 0; j < 4; ++j) acc[j] = f32x4_t{0.f, 0.f, 0.f, 0.f};

    LOAD_A(0);
    stage_B<2048>(lb, 0, &Bl[0][0], t);
    WRITE_A(0);
    __syncthreads();

    for (int s = 0; s < 32; ++s) {
        const int buf = s & 1;
        if (s < 31) {
            LOAD_A((s + 1) * 64);
            stage_B<2048>(lb, (s + 1) * 64, &Bl[buf ^ 1][0], t);
        }
        bf16x8_t af[2];
        #pragma unroll
        for (int kk = 0; kk < 2; ++kk)
            af[kk] = __builtin_bit_cast(bf16x8_t,
                *(const u32x4_t*)((const char*)(&Al[buf][0]) + offA[kk]));
        #pragma unroll
        for (int j = 0; j < 4; ++j) {
            #pragma unroll
            for (int kk = 0; kk < 2; ++kk) {
                bf16x8_t bfj = __builtin_bit_cast(bf16x8_t,
                    *(const u32x4_t*)((const char*)(&Bl[buf][0]) + offB[j][kk]));
                acc[j] = __builtin_amdgcn_mfma_f32_16x16x32_bf16(af[kk], bfj, acc[j], 0, 0, 0);
            }
        }
        if (s < 31) WRITE_A(buf ^ 1);
        __syncthreads();
    }

    const int nrow = n0 + wn * 16 + (lane >> 4) * 4;
    #pragma unroll
    for (int j = 0; j < 4; ++j) {
        int col = wh * 64 + j * 16 + fr;
        #pragma unroll
        for (int jj = 0; jj < 4; ++jj) {
            ret[((size_t)b * 4096 + nrow + jj) * 128 + col] = acc[j][jj];
        }
    }
}

// ---------------------------------------------------------------------------
extern "C" void kernel_launch(void* const* d_in, const int* in_sizes, int n_in,
                              void* d_out, int out_size, void* d_ws, size_t ws_size,
                              hipStream_t stream) {
    const float* adj    = (const float*)d_in[0];
    const float* embeds = (const float*)d_in[1];
    const int*   ntype  = (const int*)d_in[2];
    const unsigned char* mask8 = (const unsigned char*)d_in[3];
    const float* W      = (const float*)d_in[4];
    const float* bias   = (const float*)d_in[5];
    const float* gamma  = (const float*)d_in[6];
    const float* beta   = (const float*)d_in[7];
    float* ret = (float*)d_out;

    unsigned short* xT   = (unsigned short*)d_ws;                   // 8.39 MB
    unsigned short* latT = xT + (size_t)8 * 128 * 4096;             // 4.19 MB
    unsigned short* WT   = latT + (size_t)8 * 128 * 2048;           // 0.43 MB
    // ws needed: 13.0 MB

    hipLaunchKernelGGL(k0_wtrans, dim3(13), dim3(256), 0, stream, W, WT);
    hipLaunchKernelGGL(k1_typed_ln, dim3(512), dim3(256), 0, stream,
                       embeds, ntype, mask8, WT, bias, gamma, beta, xT);
    hipLaunchKernelGGL(k2_lat, dim3(512), dim3(256), 0, stream, adj, xT, latT);
    hipLaunchKernelGGL(k3_ret, dim3(1024), dim3(256), 0, stream, adj, latT, ret);
}